// Round 14
// baseline (342.477 us; speedup 1.0000x reference)
//
#include <hip/hip_runtime.h>
#include <hip/hip_bf16.h>
#include <math.h>

#define N_ATOMS  50000
#define N_MOTIFS 50000
#define N_SEG    (N_MOTIFS + N_ATOMS)   // 100000 combined segments
#define N_INC    600000
#define N_GRAPHS 512
#define H        64
#define MOTIF_DIM 94
#define HOUT     128
#define BN_EPS   1e-5f
#define NZ       101
#define SCAN_NBLK 98                    // ceil(100000/1024)
#define TL       64                     // motif rows per block
#define NBLK_L   ((N_MOTIFS + TL - 1) / TL)  // 782
#define EZCAP    1280                   // LDS edge-list cap (mean 768; global fallback)
#define NREP     32                     // BN accumulator replicas

__device__ __forceinline__ float softplus_fast(float x) {
    return fmaxf(x, 0.0f) + __logf(1.0f + __expf(-fabsf(x)));
}
__device__ __forceinline__ float gate_f(float f, float c) {
    float sig = __builtin_amdgcn_rcpf(1.0f + __expf(-f));
    return sig * softplus_fast(c);
}

// degree histogram; 4 edges per thread for atomic-latency overlap
__global__ __launch_bounds__(256) void count_kernel(const int* __restrict__ he,
                                                    unsigned* __restrict__ cnt) {
    int e0 = (blockIdx.x * 256 + threadIdx.x) * 4;
    if (e0 + 4 <= N_INC) {
        int4 s4 = *(const int4*)(he + e0);
        int4 h4 = *(const int4*)(he + N_INC + e0);
        atomicAdd(&cnt[h4.x], 1u); atomicAdd(&cnt[h4.y], 1u);
        atomicAdd(&cnt[h4.z], 1u); atomicAdd(&cnt[h4.w], 1u);
        atomicAdd(&cnt[N_MOTIFS + s4.x], 1u); atomicAdd(&cnt[N_MOTIFS + s4.y], 1u);
        atomicAdd(&cnt[N_MOTIFS + s4.z], 1u); atomicAdd(&cnt[N_MOTIFS + s4.w], 1u);
    } else {
        for (int e = e0; e < N_INC; e++) {
            atomicAdd(&cnt[he[N_INC + e]], 1u);
            atomicAdd(&cnt[N_MOTIFS + he[e]], 1u);
        }
    }
}

// phase 1: per-block (1024 elems) sums
__global__ __launch_bounds__(256) void scan_part(const unsigned* __restrict__ cnt,
                                                 unsigned* __restrict__ part) {
    __shared__ unsigned red[256];
    int b = blockIdx.x, t = threadIdx.x;
    int i0 = b * 1024 + t * 4;
    unsigned s = 0;
#pragma unroll
    for (int i = 0; i < 4; i++) { int idx = i0 + i; if (idx < N_SEG) s += cnt[idx]; }
    red[t] = s;
    __syncthreads();
    for (int off = 128; off > 0; off >>= 1) {
        if (t < off) red[t] += red[t + off];
        __syncthreads();
    }
    if (t == 0) part[b] = red[0];
}

// aux: block 0 = exclusive scan of the 98 block sums; blocks 1..NZ = projected-table
// precompute (atab_fc = table@w[0:64] interleaved; ptab_{f,c} = table@w[64:128]).
__global__ __launch_bounds__(256) void aux_kernel(const unsigned* __restrict__ part,
                                                  unsigned* __restrict__ part_pre,
                                                  const float* __restrict__ table,
                                                  const float* __restrict__ w_f,
                                                  const float* __restrict__ w_c,
                                                  float* __restrict__ atab_fc,
                                                  float* __restrict__ ptab_f,
                                                  float* __restrict__ ptab_c) {
    int t = threadIdx.x;
    if (blockIdx.x == 0) {
        __shared__ unsigned s[128];
        if (t < 128) s[t] = (t < SCAN_NBLK) ? part[t] : 0u;
        __syncthreads();
        for (int off = 1; off < 128; off <<= 1) {
            unsigned add = (t < 128 && t >= off) ? s[t - off] : 0u;
            __syncthreads();
            if (t < 128) s[t] += add;
            __syncthreads();
        }
        if (t < SCAN_NBLK) part_pre[t] = (t > 0) ? s[t - 1] : 0u;
        return;
    }
    int z = blockIdx.x - 1;
    __shared__ float trow[H];
    if (t < H) trow[t] = table[(size_t)z * H + t];
    __syncthreads();
    if (t < 128) {
        int sel = (t >= 64) ? 1 : 0;
        int jj = t & 63;
        const float* ws = sel ? w_c : w_f;
        float aacc = 0.0f, pacc = 0.0f;
        for (int k = 0; k < H; k++) {
            float tv = trow[k];
            aacc += tv * ws[(size_t)k * H + jj];
            pacc += tv * ws[(size_t)(H + k) * H + jj];
        }
        atab_fc[(size_t)z * 128 + jj * 2 + sel] = aacc;
        (sel ? ptab_c : ptab_f)[(size_t)z * H + jj] = pacc;
    }
}

// phase 3: block-local exclusive scan + global offset -> base, cur (+sentinel)
__global__ __launch_bounds__(256) void scan_down(const unsigned* __restrict__ cnt,
                                                 const unsigned* __restrict__ part_pre,
                                                 unsigned* __restrict__ base,
                                                 unsigned* __restrict__ cur) {
    __shared__ unsigned s[256];
    int b = blockIdx.x, t = threadIdx.x;
    int i0 = b * 1024 + t * 4;
    unsigned c[4];
#pragma unroll
    for (int i = 0; i < 4; i++) { int idx = i0 + i; c[i] = (idx < N_SEG) ? cnt[idx] : 0u; }
    s[t] = c[0] + c[1] + c[2] + c[3];
    __syncthreads();
    for (int off = 1; off < 256; off <<= 1) {
        unsigned add = (t >= off) ? s[t - off] : 0u;
        __syncthreads();
        s[t] += add;
        __syncthreads();
    }
    unsigned pre = part_pre[b] + ((t > 0) ? s[t - 1] : 0u);
#pragma unroll
    for (int i = 0; i < 4; i++) {
        int idx = i0 + i;
        if (idx < N_SEG) { base[idx] = pre; cur[idx] = pre; pre += c[i]; }
    }
    if (b == SCAN_NBLK - 1 && t == 255) base[N_SEG] = pre;  // sentinel = 2*N_INC
}

// XCD-partitioned CSR fill; 2 edges per iteration for more atomics in flight
__global__ __launch_bounds__(256) void fill_kernel(const int* __restrict__ he,
                                                   const int* __restrict__ atom_z,
                                                   unsigned* __restrict__ cur,
                                                   int* __restrict__ csr_val) {
    int cls = blockIdx.x & 7;
    int bi  = blockIdx.x >> 3;
    int nb  = gridDim.x >> 3;
    for (int e = (bi * 256 + threadIdx.x) * 2; e < N_INC; e += nb * 512) {
        int s0 = he[e], h0 = he[N_INC + e];
        int s1 = -1, h1 = -1;
        if (e + 1 < N_INC) { s1 = he[e + 1]; h1 = he[N_INC + e + 1]; }
        if (((h0 >> 4) & 7) == cls) {
            unsigned p = atomicAdd(&cur[h0], 1u);
            csr_val[p] = atom_z[s0];
        }
        if (h1 >= 0 && ((h1 >> 4) & 7) == cls) {
            unsigned p = atomicAdd(&cur[h1], 1u);
            csr_val[p] = atom_z[s1];
        }
        if (((s0 >> 4) & 7) == cls) {
            unsigned q = atomicAdd(&cur[N_MOTIFS + s0], 1u);
            csr_val[q] = h0;
        }
        if (s1 >= 0 && ((s1 >> 4) & 7) == cls) {
            unsigned q = atomicAdd(&cur[N_MOTIFS + s1], 1u);
            csr_val[q] = h1;
        }
    }
}

// Motif kernel, f/c split across blockIdx.y; z padded to 100 (bank-safe);
// separate contiguous output planes. 4 rows x 4 cols per thread; 8-deep gather.
__global__ __launch_bounds__(256) void motif_fused(const unsigned* __restrict__ base,
                                                   const int* __restrict__ csr_val,
                                                   const float* __restrict__ ptab_f,
                                                   const float* __restrict__ ptab_c,
                                                   const float* __restrict__ motif_attr,
                                                   const float* __restrict__ w_f,
                                                   const float* __restrict__ b_f,
                                                   const float* __restrict__ w_c,
                                                   const float* __restrict__ b_c,
                                                   float* __restrict__ m_f,
                                                   float* __restrict__ m_c) {
    __shared__ float z[TL][100];     // attr tile (94 used; stride 100 kills conflicts)
    __shared__ int   ez[EZCAP];      // block's contiguous edge list (atom types)
    __shared__ int   rowlo[TL + 1];
    __shared__ float invd[TL];
    int m0 = blockIdx.x * TL;
    int sel = blockIdx.y;            // 0 = f, 1 = c
    int tid = threadIdx.x;
    unsigned blockBase = base[m0];
    if (tid <= TL) {
        int gm = m0 + tid;
        rowlo[tid] = (int)(base[(gm < N_MOTIFS) ? gm : N_MOTIFS] - blockBase);
    }
    __syncthreads();
    if (tid < TL) {
        int d = rowlo[tid + 1] - rowlo[tid];
        invd[tid] = 1.0f / fmaxf((float)d, 1.0f);
    }
    int nE = rowlo[TL];
    int nStage = (nE < EZCAP) ? nE : EZCAP;
    for (int k = tid; k < nStage; k += 256) ez[k] = csr_val[blockBase + k];
    for (int idx = tid; idx < TL * 47; idx += 256) {
        int m = idx / 47, k2 = idx % 47;
        int gm = m0 + m;
        float2 v = make_float2(0.f, 0.f);
        if (gm < N_MOTIFS) v = ((const float2*)motif_attr)[(size_t)gm * 47 + k2];
        *(float2*)&z[m][k2 * 2] = v;
    }
    __syncthreads();

    int rg = tid >> 4;          // 16 row groups of 4
    int cg = tid & 15;          // 16 col groups of 4 (64 cols this block)
    int jj = cg * 4;
    const float* ptab = sel ? ptab_c : ptab_f;

    // ---- gather phase: projected hx rows, 8 independent loads in flight ----
    float4 bias4 = *(const float4*)((sel ? b_c : b_f) + jj);
    float acc[4][4];
#pragma unroll
    for (int i = 0; i < 4; i++) {
        int r = rg * 4 + i;
        int lo = rowlo[r], d = rowlo[r + 1] - lo;
        float g0 = 0.f, g1 = 0.f, g2 = 0.f, g3 = 0.f;
        int k = 0;
        for (; k + 8 <= d; k += 8) {
            int zz[8];
#pragma unroll
            for (int u = 0; u < 8; u++) {
                int o = lo + k + u;
                zz[u] = (o < EZCAP) ? ez[o] : csr_val[blockBase + o];
            }
            float4 p[8];
#pragma unroll
            for (int u = 0; u < 8; u++) p[u] = *(const float4*)(ptab + (size_t)zz[u] * H + jj);
#pragma unroll
            for (int u = 0; u < 8; u++) {
                g0 += p[u].x; g1 += p[u].y; g2 += p[u].z; g3 += p[u].w;
            }
        }
        for (; k < d; k++) {
            int o0 = lo + k;
            int z0 = (o0 < EZCAP) ? ez[o0] : csr_val[blockBase + o0];
            float4 p0 = *(const float4*)(ptab + (size_t)z0 * H + jj);
            g0 += p0.x; g1 += p0.y; g2 += p0.z; g3 += p0.w;
        }
        float iv = invd[r];
        acc[i][0] = bias4.x + g0 * iv;
        acc[i][1] = bias4.y + g1 * iv;
        acc[i][2] = bias4.z + g2 * iv;
        acc[i][3] = bias4.w + g3 * iv;
    }

    // ---- attr projection: K=94, w rows 128:222, unroll pinned + prefetch ----
    const float* wsrc = (sel ? w_c : w_f) + (size_t)(2 * H) * H + jj;
    float4 wb0 = *(const float4*)(wsrc);
    float4 wb1 = *(const float4*)(wsrc + H);
    float4 wb2 = *(const float4*)(wsrc + 2 * H);
    float4 wb3 = *(const float4*)(wsrc + 3 * H);
#pragma unroll 1
    for (int k = 0; k < 88; k += 4) {
        float4 nw0 = *(const float4*)(wsrc + (size_t)(k + 4) * H);
        float4 nw1 = *(const float4*)(wsrc + (size_t)(k + 5) * H);
        float4 nw2 = *(const float4*)(wsrc + (size_t)(k + 6) * H);
        float4 nw3 = *(const float4*)(wsrc + (size_t)(k + 7) * H);
        float4 zv[4];
#pragma unroll
        for (int i = 0; i < 4; i++) zv[i] = *(const float4*)&z[rg * 4 + i][k];
#pragma unroll
        for (int i = 0; i < 4; i++) {
            acc[i][0] += zv[i].x * wb0.x + zv[i].y * wb1.x + zv[i].z * wb2.x + zv[i].w * wb3.x;
            acc[i][1] += zv[i].x * wb0.y + zv[i].y * wb1.y + zv[i].z * wb2.y + zv[i].w * wb3.y;
            acc[i][2] += zv[i].x * wb0.z + zv[i].y * wb1.z + zv[i].z * wb2.z + zv[i].w * wb3.z;
            acc[i][3] += zv[i].x * wb0.w + zv[i].y * wb1.w + zv[i].z * wb2.w + zv[i].w * wb3.w;
        }
        wb0 = nw0; wb1 = nw1; wb2 = nw2; wb3 = nw3;
    }
    {   // tail k = 88..91 from wb
        float4 zv[4];
#pragma unroll
        for (int i = 0; i < 4; i++) zv[i] = *(const float4*)&z[rg * 4 + i][88];
#pragma unroll
        for (int i = 0; i < 4; i++) {
            acc[i][0] += zv[i].x * wb0.x + zv[i].y * wb1.x + zv[i].z * wb2.x + zv[i].w * wb3.x;
            acc[i][1] += zv[i].x * wb0.y + zv[i].y * wb1.y + zv[i].z * wb2.y + zv[i].w * wb3.y;
            acc[i][2] += zv[i].x * wb0.z + zv[i].y * wb1.z + zv[i].z * wb2.z + zv[i].w * wb3.z;
            acc[i][3] += zv[i].x * wb0.w + zv[i].y * wb1.w + zv[i].z * wb2.w + zv[i].w * wb3.w;
        }
    }
    {   // tail k = 92,93
        float4 w0 = *(const float4*)(wsrc + (size_t)92 * H);
        float4 w1 = *(const float4*)(wsrc + (size_t)93 * H);
        float2 zv[4];
#pragma unroll
        for (int i = 0; i < 4; i++) zv[i] = *(const float2*)&z[rg * 4 + i][92];
#pragma unroll
        for (int i = 0; i < 4; i++) {
            acc[i][0] += zv[i].x * w0.x + zv[i].y * w1.x;
            acc[i][1] += zv[i].x * w0.y + zv[i].y * w1.y;
            acc[i][2] += zv[i].x * w0.z + zv[i].y * w1.z;
            acc[i][3] += zv[i].x * w0.w + zv[i].y * w1.w;
        }
    }
    float* dst = sel ? m_c : m_f;
#pragma unroll
    for (int i = 0; i < 4; i++) {
        int gm = m0 + rg * 4 + i;
        if (gm < N_MOTIFS)
            *(float4*)&dst[(size_t)gm * H + jj] =
                make_float4(acc[i][0], acc[i][1], acc[i][2], acc[i][3]);
    }
}

// one wave per atom (contiguous mapping); 16-deep edge batching;
// fused BN column stats into NREP replicated accumulators.
__global__ __launch_bounds__(256) void msg_gather(const unsigned* __restrict__ base,
                                                  const int* __restrict__ csr_val,
                                                  const int* __restrict__ atom_z,
                                                  const float2* __restrict__ atab_fc,
                                                  const float* __restrict__ m_f,
                                                  const float* __restrict__ m_c,
                                                  float* __restrict__ out_mean,
                                                  float* __restrict__ bn_part) {
    int i = blockIdx.x * 4 + (threadIdx.x >> 6);
    int j = threadIdx.x & 63;
    int zi = atom_z[i];                          // wave-uniform -> scalar load
    float2 a = atab_fc[(size_t)zi * H + j];
    unsigned b = base[N_MOTIFS + i];
    unsigned d = base[N_MOTIFS + i + 1] - b;     // sentinel covers last atom
    float acc = 0.0f;
    unsigned k = 0;
    for (; k + 16 <= d; k += 16) {
        int hh[16];
#pragma unroll
        for (int u = 0; u < 16; u++) hh[u] = csr_val[b + k + u];
        float vf[16], vc[16];
#pragma unroll
        for (int u = 0; u < 16; u++) vf[u] = m_f[(size_t)hh[u] * H + j];
#pragma unroll
        for (int u = 0; u < 16; u++) vc[u] = m_c[(size_t)hh[u] * H + j];
#pragma unroll
        for (int u = 0; u < 16; u++) acc += gate_f(a.x + vf[u], a.y + vc[u]);
    }
    for (; k + 4 <= d; k += 4) {
        int hh[4];
#pragma unroll
        for (int u = 0; u < 4; u++) hh[u] = csr_val[b + k + u];
        float vf[4], vc[4];
#pragma unroll
        for (int u = 0; u < 4; u++) vf[u] = m_f[(size_t)hh[u] * H + j];
#pragma unroll
        for (int u = 0; u < 4; u++) vc[u] = m_c[(size_t)hh[u] * H + j];
#pragma unroll
        for (int u = 0; u < 4; u++) acc += gate_f(a.x + vf[u], a.y + vc[u]);
    }
    for (; k < d; k++) {
        int h0 = csr_val[b + k];
        acc += gate_f(a.x + m_f[(size_t)h0 * H + j], a.y + m_c[(size_t)h0 * H + j]);
    }
    float v = acc / fmaxf((float)d, 1.0f);
    out_mean[(size_t)i * H + j] = v;
    __shared__ float ssum[256];
    __shared__ float ssq[256];
    ssum[threadIdx.x] = v; ssq[threadIdx.x] = v * v;
    __syncthreads();
    if (threadIdx.x < 64) {
        float* rep = bn_part + (size_t)(blockIdx.x & (NREP - 1)) * 128;
        atomicAdd(&rep[j],      ssum[j] + ssum[64 + j] + ssum[128 + j] + ssum[192 + j]);
        atomicAdd(&rep[64 + j], ssq[j]  + ssq[64 + j]  + ssq[128 + j]  + ssq[192 + j]);
    }
}

// one block per graph: reduce BN replicas + bounds search + BN-apply + residual +
// relu + mean-pool, then the MLP head inline.
__global__ __launch_bounds__(256) void pool_head(const float* __restrict__ out_mean,
                                                 const float* __restrict__ bn_part,
                                                 const float* __restrict__ gamma,
                                                 const float* __restrict__ beta,
                                                 const int* __restrict__ atom_z,
                                                 const float* __restrict__ table,
                                                 const int* __restrict__ batch,
                                                 const float* __restrict__ w_l1,
                                                 const float* __restrict__ b_l1,
                                                 const float* __restrict__ w_out,
                                                 const float* __restrict__ b_out,
                                                 float* __restrict__ out) {
    int g = blockIdx.x;
    int tid = threadIdx.x;
    __shared__ int bounds[2];
    __shared__ float red[256];
    __shared__ float gv[H];
    __shared__ float red2[HOUT];
    __shared__ float bnred[128];
    if (tid < 2) {
        int target = g + tid;
        int lo = 0, hi = N_ATOMS;
        while (lo < hi) {
            int mid = (lo + hi) >> 1;
            if (batch[mid] < target) lo = mid + 1; else hi = mid;
        }
        bounds[tid] = lo;
    }
    if (tid < 128) {
        float s = 0.0f;
        for (int r = 0; r < NREP; r++) s += bn_part[(size_t)r * 128 + tid];
        bnred[tid] = s;
    }
    __syncthreads();
    int s = bounds[0], e = bounds[1];
    int j = tid & 63, w = tid >> 6;
    const float invN = 1.0f / (float)N_ATOMS;
    float mu = bnred[j] * invN;
    float var = bnred[64 + j] * invN - mu * mu;
    float rstd = 1.0f / sqrtf(var + BN_EPS);
    float gm = gamma[j], bt = beta[j];
    float acc = 0.0f;
    for (int i = s + w; i < e; i += 4) {
        float d = out_mean[(size_t)i * H + j];
        float xv = table[(size_t)atom_z[i] * H + j];
        float o = (d - mu) * rstd * gm + bt;
        acc += fmaxf(o + xv, 0.0f);
    }
    red[tid] = acc;
    __syncthreads();
    if (tid < 64)
        gv[j] = (red[j] + red[64 + j] + red[128 + j] + red[192 + j])
                / fmaxf((float)(e - s), 1.0f);
    __syncthreads();
    if (tid < HOUT) {
        float a2 = b_l1[tid];
        for (int k = 0; k < H; k++) a2 += gv[k] * w_l1[(size_t)k * HOUT + tid];
        red2[tid] = softplus_fast(a2) * w_out[tid];
    }
    __syncthreads();
    for (int st = 64; st > 0; st >>= 1) {
        if (tid < st) red2[tid] += red2[tid + st];
        __syncthreads();
    }
    if (tid == 0) out[g] = red2[0] + b_out[0];
}

extern "C" void kernel_launch(void* const* d_in, const int* in_sizes, int n_in,
                              void* d_out, int out_size, void* d_ws, size_t ws_size,
                              hipStream_t stream) {
    const int*   atom_z     = (const int*)  d_in[0];
    const float* motif_attr = (const float*)d_in[1];
    const int*   he         = (const int*)  d_in[2];
    const int*   batch      = (const int*)  d_in[3];
    const float* table      = (const float*)d_in[4];
    const float* w_f        = (const float*)d_in[5];
    const float* b_f        = (const float*)d_in[6];
    const float* w_c        = (const float*)d_in[7];
    const float* b_c        = (const float*)d_in[8];
    const float* gamma      = (const float*)d_in[9];
    const float* beta       = (const float*)d_in[10];
    const float* w_l1       = (const float*)d_in[11];
    const float* b_l1       = (const float*)d_in[12];
    const float* w_out      = (const float*)d_in[13];
    const float* b_out      = (const float*)d_in[14];
    float* out = (float*)d_out;

    // ---- workspace layout ----
    unsigned* cnt     = (unsigned*)d_ws;                   // 100,000 (zeroed)
    float*    bn_part = (float*)(cnt + N_SEG);             // 32*128 (zeroed)
    char*     zero_end = (char*)(bn_part + NREP * 128);
    unsigned* base     = (unsigned*)zero_end;              // 100,001 (+sentinel +pad)
    unsigned* cur      = base + N_SEG + 4;                 // 100,000
    unsigned* part     = cur + N_SEG;                      // 128
    unsigned* part_pre = part + 128;                       // 128
    int*      csr_val  = (int*)(part_pre + 128);           // 1,200,000
    float*    atab_fc  = (float*)(csr_val + 2 * N_INC);    // 101*128
    float*    ptab_f   = atab_fc + (size_t)NZ * 128;       // 101*64
    float*    ptab_c   = ptab_f + (size_t)NZ * H;          // 101*64
    float*    m_f      = ptab_c + (size_t)NZ * H;          // 3.2M
    float*    m_c      = m_f + (size_t)N_MOTIFS * H;       // 3.2M
    float*    out_mean = m_c + (size_t)N_MOTIFS * H;       // 3.2M

    size_t zero_bytes = (size_t)(zero_end - (char*)d_ws);
    hipMemsetAsync(d_ws, 0, zero_bytes, stream);

    count_kernel<<<(N_INC / 4 + 255) / 256, 256, 0, stream>>>(he, cnt);
    scan_part<<<SCAN_NBLK, 256, 0, stream>>>(cnt, part);
    aux_kernel<<<1 + NZ, 256, 0, stream>>>(part, part_pre, table, w_f, w_c,
                                           atab_fc, ptab_f, ptab_c);
    scan_down<<<SCAN_NBLK, 256, 0, stream>>>(cnt, part_pre, base, cur);
    fill_kernel<<<1024, 256, 0, stream>>>(he, atom_z, cur, csr_val);
    motif_fused<<<dim3(NBLK_L, 2), 256, 0, stream>>>(base, csr_val, ptab_f, ptab_c,
                                                     motif_attr, w_f, b_f, w_c, b_c,
                                                     m_f, m_c);
    msg_gather<<<N_ATOMS / 4, 256, 0, stream>>>(base, csr_val, atom_z,
                                                (const float2*)atab_fc, m_f, m_c,
                                                out_mean, bn_part);
    pool_head<<<N_GRAPHS, 256, 0, stream>>>(out_mean, bn_part, gamma, beta,
                                            atom_z, table, batch,
                                            w_l1, b_l1, w_out, b_out, out);
}

// Round 15
// 334.458 us; speedup vs baseline: 1.0240x; 1.0240x over previous
//
#include <hip/hip_runtime.h>
#include <hip/hip_bf16.h>
#include <math.h>

#define N_ATOMS  50000
#define N_MOTIFS 50000
#define N_SEG    (N_MOTIFS + N_ATOMS)   // 100000 combined segments
#define N_INC    600000
#define N_GRAPHS 512
#define H        64
#define MOTIF_DIM 94
#define HOUT     128
#define BN_EPS   1e-5f
#define NZ       101
#define SCAN_NBLK 98                    // ceil(100000/1024)
#define TL       64                     // motif rows per block
#define NBLK_L   ((N_MOTIFS + TL - 1) / TL)  // 782
#define EZCAP    1280                   // LDS edge-list cap (mean 768; global fallback)
#define NREP     32                     // BN accumulator replicas

__device__ __forceinline__ float softplus_fast(float x) {
    return fmaxf(x, 0.0f) + __logf(1.0f + __expf(-fabsf(x)));
}
__device__ __forceinline__ float gate_f(float f, float c) {
    float sig = __builtin_amdgcn_rcpf(1.0f + __expf(-f));
    return sig * softplus_fast(c);
}

// degree histogram (R13 form — R14's 4-edge variant showed a pathological replay)
__global__ __launch_bounds__(256) void count_kernel(const int* __restrict__ he,
                                                    unsigned* __restrict__ cnt) {
    int e = blockIdx.x * 256 + threadIdx.x;
    if (e >= N_INC) return;
    atomicAdd(&cnt[he[N_INC + e]], 1u);
    atomicAdd(&cnt[N_MOTIFS + he[e]], 1u);
}

// phase 1: per-block (1024 elems) sums
__global__ __launch_bounds__(256) void scan_part(const unsigned* __restrict__ cnt,
                                                 unsigned* __restrict__ part) {
    __shared__ unsigned red[256];
    int b = blockIdx.x, t = threadIdx.x;
    int i0 = b * 1024 + t * 4;
    unsigned s = 0;
#pragma unroll
    for (int i = 0; i < 4; i++) { int idx = i0 + i; if (idx < N_SEG) s += cnt[idx]; }
    red[t] = s;
    __syncthreads();
    for (int off = 128; off > 0; off >>= 1) {
        if (t < off) red[t] += red[t + off];
        __syncthreads();
    }
    if (t == 0) part[b] = red[0];
}

// aux: block 0 = exclusive scan of block sums; blocks 1..NZ = projected tables
__global__ __launch_bounds__(256) void aux_kernel(const unsigned* __restrict__ part,
                                                  unsigned* __restrict__ part_pre,
                                                  const float* __restrict__ table,
                                                  const float* __restrict__ w_f,
                                                  const float* __restrict__ w_c,
                                                  float* __restrict__ atab_fc,
                                                  float* __restrict__ ptab_f,
                                                  float* __restrict__ ptab_c) {
    int t = threadIdx.x;
    if (blockIdx.x == 0) {
        __shared__ unsigned s[128];
        if (t < 128) s[t] = (t < SCAN_NBLK) ? part[t] : 0u;
        __syncthreads();
        for (int off = 1; off < 128; off <<= 1) {
            unsigned add = (t < 128 && t >= off) ? s[t - off] : 0u;
            __syncthreads();
            if (t < 128) s[t] += add;
            __syncthreads();
        }
        if (t < SCAN_NBLK) part_pre[t] = (t > 0) ? s[t - 1] : 0u;
        return;
    }
    int z = blockIdx.x - 1;
    __shared__ float trow[H];
    if (t < H) trow[t] = table[(size_t)z * H + t];
    __syncthreads();
    if (t < 128) {
        int sel = (t >= 64) ? 1 : 0;
        int jj = t & 63;
        const float* ws = sel ? w_c : w_f;
        float aacc = 0.0f, pacc = 0.0f;
        for (int k = 0; k < H; k++) {
            float tv = trow[k];
            aacc += tv * ws[(size_t)k * H + jj];
            pacc += tv * ws[(size_t)(H + k) * H + jj];
        }
        atab_fc[(size_t)z * 128 + jj * 2 + sel] = aacc;
        (sel ? ptab_c : ptab_f)[(size_t)z * H + jj] = pacc;
    }
}

// phase 3: block-local exclusive scan + global offset -> base, cur (+sentinel)
__global__ __launch_bounds__(256) void scan_down(const unsigned* __restrict__ cnt,
                                                 const unsigned* __restrict__ part_pre,
                                                 unsigned* __restrict__ base,
                                                 unsigned* __restrict__ cur) {
    __shared__ unsigned s[256];
    int b = blockIdx.x, t = threadIdx.x;
    int i0 = b * 1024 + t * 4;
    unsigned c[4];
#pragma unroll
    for (int i = 0; i < 4; i++) { int idx = i0 + i; c[i] = (idx < N_SEG) ? cnt[idx] : 0u; }
    s[t] = c[0] + c[1] + c[2] + c[3];
    __syncthreads();
    for (int off = 1; off < 256; off <<= 1) {
        unsigned add = (t >= off) ? s[t - off] : 0u;
        __syncthreads();
        s[t] += add;
        __syncthreads();
    }
    unsigned pre = part_pre[b] + ((t > 0) ? s[t - 1] : 0u);
#pragma unroll
    for (int i = 0; i < 4; i++) {
        int idx = i0 + i;
        if (idx < N_SEG) { base[idx] = pre; cur[idx] = pre; pre += c[i]; }
    }
    if (b == SCAN_NBLK - 1 && t == 255) base[N_SEG] = pre;  // sentinel = 2*N_INC
}

// XCD-partitioned CSR fill (R13 form)
__global__ __launch_bounds__(256) void fill_kernel(const int* __restrict__ he,
                                                   const int* __restrict__ atom_z,
                                                   unsigned* __restrict__ cur,
                                                   int* __restrict__ csr_val) {
    int cls = blockIdx.x & 7;
    int bi  = blockIdx.x >> 3;
    int nb  = gridDim.x >> 3;
    for (int e = bi * 256 + threadIdx.x; e < N_INC; e += nb * 256) {
        int s = he[e];
        int h = he[N_INC + e];
        if (((h >> 4) & 7) == cls) {
            unsigned p = atomicAdd(&cur[h], 1u);
            csr_val[p] = atom_z[s];
        }
        if (((s >> 4) & 7) == cls) {
            unsigned q = atomicAdd(&cur[N_MOTIFS + s], 1u);
            csr_val[q] = h;
        }
    }
}

// Motif kernel, f/c split across blockIdx.y; z padded to 100 (bank-safe);
// separate contiguous output planes. 4 rows x 4 cols per thread; 8-deep gather.
__global__ __launch_bounds__(256) void motif_fused(const unsigned* __restrict__ base,
                                                   const int* __restrict__ csr_val,
                                                   const float* __restrict__ ptab_f,
                                                   const float* __restrict__ ptab_c,
                                                   const float* __restrict__ motif_attr,
                                                   const float* __restrict__ w_f,
                                                   const float* __restrict__ b_f,
                                                   const float* __restrict__ w_c,
                                                   const float* __restrict__ b_c,
                                                   float* __restrict__ m_f,
                                                   float* __restrict__ m_c) {
    __shared__ float z[TL][100];
    __shared__ int   ez[EZCAP];
    __shared__ int   rowlo[TL + 1];
    __shared__ float invd[TL];
    int m0 = blockIdx.x * TL;
    int sel = blockIdx.y;
    int tid = threadIdx.x;
    unsigned blockBase = base[m0];
    if (tid <= TL) {
        int gm = m0 + tid;
        rowlo[tid] = (int)(base[(gm < N_MOTIFS) ? gm : N_MOTIFS] - blockBase);
    }
    __syncthreads();
    if (tid < TL) {
        int d = rowlo[tid + 1] - rowlo[tid];
        invd[tid] = 1.0f / fmaxf((float)d, 1.0f);
    }
    int nE = rowlo[TL];
    int nStage = (nE < EZCAP) ? nE : EZCAP;
    for (int k = tid; k < nStage; k += 256) ez[k] = csr_val[blockBase + k];
    for (int idx = tid; idx < TL * 47; idx += 256) {
        int m = idx / 47, k2 = idx % 47;
        int gm = m0 + m;
        float2 v = make_float2(0.f, 0.f);
        if (gm < N_MOTIFS) v = ((const float2*)motif_attr)[(size_t)gm * 47 + k2];
        *(float2*)&z[m][k2 * 2] = v;
    }
    __syncthreads();

    int rg = tid >> 4;
    int cg = tid & 15;
    int jj = cg * 4;
    const float* ptab = sel ? ptab_c : ptab_f;

    float4 bias4 = *(const float4*)((sel ? b_c : b_f) + jj);
    float acc[4][4];
#pragma unroll
    for (int i = 0; i < 4; i++) {
        int r = rg * 4 + i;
        int lo = rowlo[r], d = rowlo[r + 1] - lo;
        float g0 = 0.f, g1 = 0.f, g2 = 0.f, g3 = 0.f;
        int k = 0;
        for (; k + 8 <= d; k += 8) {
            int zz[8];
#pragma unroll
            for (int u = 0; u < 8; u++) {
                int o = lo + k + u;
                zz[u] = (o < EZCAP) ? ez[o] : csr_val[blockBase + o];
            }
            float4 p[8];
#pragma unroll
            for (int u = 0; u < 8; u++) p[u] = *(const float4*)(ptab + (size_t)zz[u] * H + jj);
#pragma unroll
            for (int u = 0; u < 8; u++) {
                g0 += p[u].x; g1 += p[u].y; g2 += p[u].z; g3 += p[u].w;
            }
        }
        for (; k < d; k++) {
            int o0 = lo + k;
            int z0 = (o0 < EZCAP) ? ez[o0] : csr_val[blockBase + o0];
            float4 p0 = *(const float4*)(ptab + (size_t)z0 * H + jj);
            g0 += p0.x; g1 += p0.y; g2 += p0.z; g3 += p0.w;
        }
        float iv = invd[r];
        acc[i][0] = bias4.x + g0 * iv;
        acc[i][1] = bias4.y + g1 * iv;
        acc[i][2] = bias4.z + g2 * iv;
        acc[i][3] = bias4.w + g3 * iv;
    }

    const float* wsrc = (sel ? w_c : w_f) + (size_t)(2 * H) * H + jj;
    float4 wb0 = *(const float4*)(wsrc);
    float4 wb1 = *(const float4*)(wsrc + H);
    float4 wb2 = *(const float4*)(wsrc + 2 * H);
    float4 wb3 = *(const float4*)(wsrc + 3 * H);
#pragma unroll 1
    for (int k = 0; k < 88; k += 4) {
        float4 nw0 = *(const float4*)(wsrc + (size_t)(k + 4) * H);
        float4 nw1 = *(const float4*)(wsrc + (size_t)(k + 5) * H);
        float4 nw2 = *(const float4*)(wsrc + (size_t)(k + 6) * H);
        float4 nw3 = *(const float4*)(wsrc + (size_t)(k + 7) * H);
        float4 zv[4];
#pragma unroll
        for (int i = 0; i < 4; i++) zv[i] = *(const float4*)&z[rg * 4 + i][k];
#pragma unroll
        for (int i = 0; i < 4; i++) {
            acc[i][0] += zv[i].x * wb0.x + zv[i].y * wb1.x + zv[i].z * wb2.x + zv[i].w * wb3.x;
            acc[i][1] += zv[i].x * wb0.y + zv[i].y * wb1.y + zv[i].z * wb2.y + zv[i].w * wb3.y;
            acc[i][2] += zv[i].x * wb0.z + zv[i].y * wb1.z + zv[i].z * wb2.z + zv[i].w * wb3.z;
            acc[i][3] += zv[i].x * wb0.w + zv[i].y * wb1.w + zv[i].z * wb2.w + zv[i].w * wb3.w;
        }
        wb0 = nw0; wb1 = nw1; wb2 = nw2; wb3 = nw3;
    }
    {   // tail k = 88..91 from wb
        float4 zv[4];
#pragma unroll
        for (int i = 0; i < 4; i++) zv[i] = *(const float4*)&z[rg * 4 + i][88];
#pragma unroll
        for (int i = 0; i < 4; i++) {
            acc[i][0] += zv[i].x * wb0.x + zv[i].y * wb1.x + zv[i].z * wb2.x + zv[i].w * wb3.x;
            acc[i][1] += zv[i].x * wb0.y + zv[i].y * wb1.y + zv[i].z * wb2.y + zv[i].w * wb3.y;
            acc[i][2] += zv[i].x * wb0.z + zv[i].y * wb1.z + zv[i].z * wb2.z + zv[i].w * wb3.z;
            acc[i][3] += zv[i].x * wb0.w + zv[i].y * wb1.w + zv[i].z * wb2.w + zv[i].w * wb3.w;
        }
    }
    {   // tail k = 92,93
        float4 w0 = *(const float4*)(wsrc + (size_t)92 * H);
        float4 w1 = *(const float4*)(wsrc + (size_t)93 * H);
        float2 zv[4];
#pragma unroll
        for (int i = 0; i < 4; i++) zv[i] = *(const float2*)&z[rg * 4 + i][92];
#pragma unroll
        for (int i = 0; i < 4; i++) {
            acc[i][0] += zv[i].x * w0.x + zv[i].y * w1.x;
            acc[i][1] += zv[i].x * w0.y + zv[i].y * w1.y;
            acc[i][2] += zv[i].x * w0.z + zv[i].y * w1.z;
            acc[i][3] += zv[i].x * w0.w + zv[i].y * w1.w;
        }
    }
    float* dst = sel ? m_c : m_f;
#pragma unroll
    for (int i = 0; i < 4; i++) {
        int gm = m0 + rg * 4 + i;
        if (gm < N_MOTIFS)
            *(float4*)&dst[(size_t)gm * H + jj] =
                make_float4(acc[i][0], acc[i][1], acc[i][2], acc[i][3]);
    }
}

// interleave m_f, m_c planes into m_fc (f,c adjacent) — one 512B row per motif
__global__ __launch_bounds__(256) void interleave_kernel(const float* __restrict__ m_f,
                                                         const float* __restrict__ m_c,
                                                         float* __restrict__ m_fc) {
    size_t idx = (size_t)blockIdx.x * 256 + threadIdx.x;   // one per 2 elems
    float2 f = ((const float2*)m_f)[idx];
    float2 c = ((const float2*)m_c)[idx];
    ((float4*)m_fc)[idx] = make_float4(f.x, c.x, f.y, c.y);
}

// one wave per atom (contiguous mapping); 8-deep edge batching; ONE float2 load per
// edge from interleaved m_fc; fused BN stats into NREP replicas.
__global__ __launch_bounds__(256) void msg_gather(const unsigned* __restrict__ base,
                                                  const int* __restrict__ csr_val,
                                                  const int* __restrict__ atom_z,
                                                  const float2* __restrict__ atab_fc,
                                                  const float2* __restrict__ m_fc,
                                                  float* __restrict__ out_mean,
                                                  float* __restrict__ bn_part) {
    int i = blockIdx.x * 4 + (threadIdx.x >> 6);
    int j = threadIdx.x & 63;
    int zi = atom_z[i];                          // wave-uniform -> scalar load
    float2 a = atab_fc[(size_t)zi * H + j];
    unsigned b = base[N_MOTIFS + i];
    unsigned d = base[N_MOTIFS + i + 1] - b;     // sentinel covers last atom
    float acc = 0.0f;
    unsigned k = 0;
    for (; k + 8 <= d; k += 8) {
        int hh[8];
#pragma unroll
        for (int u = 0; u < 8; u++) hh[u] = csr_val[b + k + u];
        float2 v[8];
#pragma unroll
        for (int u = 0; u < 8; u++) v[u] = m_fc[(size_t)hh[u] * H + j];
#pragma unroll
        for (int u = 0; u < 8; u++) acc += gate_f(a.x + v[u].x, a.y + v[u].y);
    }
    for (; k + 2 <= d; k += 2) {
        int h0 = csr_val[b + k], h1 = csr_val[b + k + 1];
        float2 v0 = m_fc[(size_t)h0 * H + j];
        float2 v1 = m_fc[(size_t)h1 * H + j];
        acc += gate_f(a.x + v0.x, a.y + v0.y) + gate_f(a.x + v1.x, a.y + v1.y);
    }
    for (; k < d; k++) {
        int h0 = csr_val[b + k];
        float2 v0 = m_fc[(size_t)h0 * H + j];
        acc += gate_f(a.x + v0.x, a.y + v0.y);
    }
    float v = acc / fmaxf((float)d, 1.0f);
    out_mean[(size_t)i * H + j] = v;
    __shared__ float ssum[256];
    __shared__ float ssq[256];
    ssum[threadIdx.x] = v; ssq[threadIdx.x] = v * v;
    __syncthreads();
    if (threadIdx.x < 64) {
        float* rep = bn_part + (size_t)(blockIdx.x & (NREP - 1)) * 128;
        atomicAdd(&rep[j],      ssum[j] + ssum[64 + j] + ssum[128 + j] + ssum[192 + j]);
        atomicAdd(&rep[64 + j], ssq[j]  + ssq[64 + j]  + ssq[128 + j]  + ssq[192 + j]);
    }
}

// one block per graph: reduce BN replicas + bounds search + BN-apply + residual +
// relu + mean-pool, then the MLP head inline.
__global__ __launch_bounds__(256) void pool_head(const float* __restrict__ out_mean,
                                                 const float* __restrict__ bn_part,
                                                 const float* __restrict__ gamma,
                                                 const float* __restrict__ beta,
                                                 const int* __restrict__ atom_z,
                                                 const float* __restrict__ table,
                                                 const int* __restrict__ batch,
                                                 const float* __restrict__ w_l1,
                                                 const float* __restrict__ b_l1,
                                                 const float* __restrict__ w_out,
                                                 const float* __restrict__ b_out,
                                                 float* __restrict__ out) {
    int g = blockIdx.x;
    int tid = threadIdx.x;
    __shared__ int bounds[2];
    __shared__ float red[256];
    __shared__ float gv[H];
    __shared__ float red2[HOUT];
    __shared__ float bnred[128];
    if (tid < 2) {
        int target = g + tid;
        int lo = 0, hi = N_ATOMS;
        while (lo < hi) {
            int mid = (lo + hi) >> 1;
            if (batch[mid] < target) lo = mid + 1; else hi = mid;
        }
        bounds[tid] = lo;
    }
    if (tid < 128) {
        float s = 0.0f;
        for (int r = 0; r < NREP; r++) s += bn_part[(size_t)r * 128 + tid];
        bnred[tid] = s;
    }
    __syncthreads();
    int s = bounds[0], e = bounds[1];
    int j = tid & 63, w = tid >> 6;
    const float invN = 1.0f / (float)N_ATOMS;
    float mu = bnred[j] * invN;
    float var = bnred[64 + j] * invN - mu * mu;
    float rstd = 1.0f / sqrtf(var + BN_EPS);
    float gm = gamma[j], bt = beta[j];
    float acc = 0.0f;
    for (int i = s + w; i < e; i += 4) {
        float d = out_mean[(size_t)i * H + j];
        float xv = table[(size_t)atom_z[i] * H + j];
        float o = (d - mu) * rstd * gm + bt;
        acc += fmaxf(o + xv, 0.0f);
    }
    red[tid] = acc;
    __syncthreads();
    if (tid < 64)
        gv[j] = (red[j] + red[64 + j] + red[128 + j] + red[192 + j])
                / fmaxf((float)(e - s), 1.0f);
    __syncthreads();
    if (tid < HOUT) {
        float a2 = b_l1[tid];
        for (int k = 0; k < H; k++) a2 += gv[k] * w_l1[(size_t)k * HOUT + tid];
        red2[tid] = softplus_fast(a2) * w_out[tid];
    }
    __syncthreads();
    for (int st = 64; st > 0; st >>= 1) {
        if (tid < st) red2[tid] += red2[tid + st];
        __syncthreads();
    }
    if (tid == 0) out[g] = red2[0] + b_out[0];
}

extern "C" void kernel_launch(void* const* d_in, const int* in_sizes, int n_in,
                              void* d_out, int out_size, void* d_ws, size_t ws_size,
                              hipStream_t stream) {
    const int*   atom_z     = (const int*)  d_in[0];
    const float* motif_attr = (const float*)d_in[1];
    const int*   he         = (const int*)  d_in[2];
    const int*   batch      = (const int*)  d_in[3];
    const float* table      = (const float*)d_in[4];
    const float* w_f        = (const float*)d_in[5];
    const float* b_f        = (const float*)d_in[6];
    const float* w_c        = (const float*)d_in[7];
    const float* b_c        = (const float*)d_in[8];
    const float* gamma      = (const float*)d_in[9];
    const float* beta       = (const float*)d_in[10];
    const float* w_l1       = (const float*)d_in[11];
    const float* b_l1       = (const float*)d_in[12];
    const float* w_out      = (const float*)d_in[13];
    const float* b_out      = (const float*)d_in[14];
    float* out = (float*)d_out;

    // ---- workspace layout ----
    unsigned* cnt     = (unsigned*)d_ws;                   // 100,000 (zeroed)
    float*    bn_part = (float*)(cnt + N_SEG);             // 32*128 (zeroed)
    char*     zero_end = (char*)(bn_part + NREP * 128);
    unsigned* base     = (unsigned*)zero_end;              // 100,001 (+sentinel +pad)
    unsigned* cur      = base + N_SEG + 4;                 // 100,000
    unsigned* part     = cur + N_SEG;                      // 128
    unsigned* part_pre = part + 128;                       // 128
    int*      csr_val  = (int*)(part_pre + 128);           // 1,200,000
    float*    atab_fc  = (float*)(csr_val + 2 * N_INC);    // 101*128
    float*    ptab_f   = atab_fc + (size_t)NZ * 128;       // 101*64
    float*    ptab_c   = ptab_f + (size_t)NZ * H;          // 101*64
    float*    m_f      = ptab_c + (size_t)NZ * H;          // 3.2M
    float*    m_c      = m_f + (size_t)N_MOTIFS * H;       // 3.2M
    float*    m_fc     = m_c + (size_t)N_MOTIFS * H;       // 6.4M interleaved
    float*    out_mean = m_fc + (size_t)N_MOTIFS * H * 2;  // 3.2M

    size_t zero_bytes = (size_t)(zero_end - (char*)d_ws);
    hipMemsetAsync(d_ws, 0, zero_bytes, stream);

    count_kernel<<<(N_INC + 255) / 256, 256, 0, stream>>>(he, cnt);
    scan_part<<<SCAN_NBLK, 256, 0, stream>>>(cnt, part);
    aux_kernel<<<1 + NZ, 256, 0, stream>>>(part, part_pre, table, w_f, w_c,
                                           atab_fc, ptab_f, ptab_c);
    scan_down<<<SCAN_NBLK, 256, 0, stream>>>(cnt, part_pre, base, cur);
    fill_kernel<<<1024, 256, 0, stream>>>(he, atom_z, cur, csr_val);
    motif_fused<<<dim3(NBLK_L, 2), 256, 0, stream>>>(base, csr_val, ptab_f, ptab_c,
                                                     motif_attr, w_f, b_f, w_c, b_c,
                                                     m_f, m_c);
    interleave_kernel<<<(N_MOTIFS * H / 2) / 256, 256, 0, stream>>>(m_f, m_c, m_fc);
    msg_gather<<<N_ATOMS / 4, 256, 0, stream>>>(base, csr_val, atom_z,
                                                (const float2*)atab_fc,
                                                (const float2*)m_fc,
                                                out_mean, bn_part);
    pool_head<<<N_GRAPHS, 256, 0, stream>>>(out_mean, bn_part, gamma, beta,
                                            atom_z, table, batch,
                                            w_l1, b_l1, w_out, b_out, out);
}